// Round 6
// baseline (375.454 us; speedup 1.0000x reference)
//
#include <hip/hip_runtime.h>
#include <math.h>

#define NH 4
#define DIM 512
#define VDIM 512
#define QDIM 1024
#define KS 100
#define KN 100
#define TEMPERATURE 0.5f
#define BS 8
#define TS 2048
#define NHD (NH * DIM)          // 2048

// workspace layout (floats)
#define WS_QUERY  0                       // 16384
#define WS_QTAB   16384                   // 202*512 = 103424
#define WS_ENERGY 119808                  // 65536
#define WS_CTX    185344                  // 16384
#define WS_LOCI   201728                  // 8*512 = 4096
#define WS_P      205824                  // 202*100 = 20200
#define WS_F32_END 226028                 // *4 bytes
// bf16 region: enc_bf [8388608 el], wk_bf [1048576], wv_bf [1048576],
//              value [33554432 el] (only if ws_size allows)
#define WS_NEED_BIG (WS_F32_END * 4ull + 2ull * (8388608 + 1048576 + 1048576 + 33554432))

typedef __bf16 bf16x8 __attribute__((ext_vector_type(8)));
typedef __bf16 bf16x4 __attribute__((ext_vector_type(4)));
typedef float  f32x4  __attribute__((ext_vector_type(4)));

#define AS1(p) ((const __attribute__((address_space(1))) void*)(p))
#define AS3(p) ((__attribute__((address_space(3))) void*)(p))

__device__ __forceinline__ float fast_tanh(float x) {
    float xc = fminf(fmaxf(x, -9.0f), 9.0f);
    float e = __expf(2.0f * xc);
    return __fdividef(e - 1.0f, e + 1.0f);
}

// ---------------------------------------------------------------------------
// fp32 -> bf16 conversion, all three tensors in one launch
// ---------------------------------------------------------------------------
#define NE4 (BS * TS * VDIM / 4)      // 2097152
#define NW4 (NHD * VDIM / 4)          // 262144
__global__ void k_cvt3(const float* __restrict__ enc, const float* __restrict__ Wk,
                       const float* __restrict__ Wv, __bf16* __restrict__ enc_bf,
                       __bf16* __restrict__ wk_bf, __bf16* __restrict__ wv_bf) {
    int i = blockIdx.x * blockDim.x + threadIdx.x;
    const float* src; __bf16* dst; int k;
    if (i < NE4)                { src = enc; dst = enc_bf; k = i; }
    else if (i < NE4 + NW4)     { src = Wk;  dst = wk_bf;  k = i - NE4; }
    else                        { src = Wv;  dst = wv_bf;  k = i - NE4 - NW4; }
    float4 v = ((const float4*)src)[k];
    bf16x4 o;
    o[0] = (__bf16)v.x; o[1] = (__bf16)v.y; o[2] = (__bf16)v.z; o[3] = (__bf16)v.w;
    ((bf16x4*)dst)[k] = o;
}

// ---------------------------------------------------------------------------
// query[b, o] = tanh(dec_state[b,:] . Wq[o,:] + bq[o]);  one wave per output
// ---------------------------------------------------------------------------
__global__ void k_query(const float* __restrict__ dec, const float* __restrict__ Wq,
                        const float* __restrict__ bq, float* __restrict__ query) {
    int w = (blockIdx.x * blockDim.x + threadIdx.x) >> 6;
    int lane = threadIdx.x & 63;
    int b = w >> 11;
    int o = w & 2047;
    const float* dr = dec + b * QDIM;
    const float* wr = Wq + o * QDIM;
    float s = 0.f;
    #pragma unroll
    for (int i = 0; i < QDIM / 64; ++i) s = fmaf(dr[lane + 64 * i], wr[lane + 64 * i], s);
    #pragma unroll
    for (int off = 32; off > 0; off >>= 1) s += __shfl_down(s, off);
    if (lane == 0) query[b * NHD + o] = tanhf(s + bq[o]);
}

// ---------------------------------------------------------------------------
// P[j][k] = sum_{dt<j} sum_h convw[k,h,dt]  -- one linear sweep per k.
// ---------------------------------------------------------------------------
__global__ void k_prefix(const float* __restrict__ convw, float* __restrict__ P) {
    int k = threadIdx.x;
    if (k >= KN) return;
    const float* wr = convw + k * (NH * (2 * KS + 1));
    float acc = 0.f;
    P[k] = 0.f;
    for (int dt = 0; dt < 2 * KS + 1; ++dt) {
        acc += wr[dt] + wr[201 + dt] + wr[402 + dt] + wr[603 + dt];
        P[(dt + 1) * KN + k] = acc;
    }
}

// ---------------------------------------------------------------------------
// Qtab[j,d] = sum_k projw[d,k] * P[j,k]
// ---------------------------------------------------------------------------
__global__ void k_qtab(const float* __restrict__ P, const float* __restrict__ projw,
                       float* __restrict__ Qtab) {
    int j = blockIdx.x;       // 0..201
    __shared__ float Pc[KN];
    int tid = threadIdx.x;    // 512
    if (tid < KN) Pc[tid] = P[j * KN + tid];
    __syncthreads();
    const float* pr = projw + tid * KN;
    float s = 0.f;
    #pragma unroll 4
    for (int k = 0; k < KN; ++k) s = fmaf(pr[k], Pc[k], s);
    Qtab[j * DIM + tid] = s;
}

// ---------------------------------------------------------------------------
// locI[b,d] = tanh((Qtab[2KS+1,d]-Qtab[0,d])/len_b)  (interior-t loc value)
// ---------------------------------------------------------------------------
__global__ void k_locI(const float* __restrict__ Qtab, const int* __restrict__ enc_len,
                       float* __restrict__ locI) {
    int idx = blockIdx.x * blockDim.x + threadIdx.x;   // BS*DIM
    int b = idx >> 9, d = idx & (DIM - 1);
    float inv_len = 1.0f / (float)enc_len[b];
    locI[idx] = fast_tanh((Qtab[(2 * KS + 1) * DIM + d] - Qtab[d]) * inv_len);
}

// ===========================================================================
// GEMM core v2: 128x128 tile, BK=32, 512 threads (8 waves, 2x4 grid, wave
// tile 64x32), double-buffered LDS, one barrier/iter, and — the point —
// ALL LDS/global addresses are loop-invariant (swizzle term is i/k-indep
// at BK=32), so the K-loop body is just 8 ds_read_b128 + 16 MFMA + 3 loads.
// Swizzle: phys chunk c = j ^ (m&3) ^ ((m>>2)&3)  (2-way-free frag reads,
// 64B-coalesced staging).  DOV=1 adds the second B matrix (value GEMM).
// ===========================================================================
#define GEMM32(B1ptr, B2ptr, DOV)                                                  \
    const int t0 = blockIdx.x * 128;                                                \
    const int n0 = blockIdx.y * 128;                                                \
    const int b  = blockIdx.z;                                                      \
    const int len = enc_len[b];                                                     \
    if (t0 >= len) return;                                                          \
    const int tid = threadIdx.x;                                                    \
    const int w = tid >> 6, lane = tid & 63;                                        \
    const int wy = w >> 2, wx = w & 3;                                              \
    const int col = lane & 15, quad = lane >> 4;                                    \
    __shared__ __bf16 Ash[2 * 4096];                                                \
    __shared__ __bf16 B1sh[2 * 4096];                                               \
    __shared__ __bf16 B2sh[2 * 4096];                                               \
    f32x4 acc1[4][2], acc2[4][2];                                                   \
    _Pragma("unroll")                                                               \
    for (int i = 0; i < 4; ++i)                                                     \
        _Pragma("unroll")                                                           \
        for (int j = 0; j < 2; ++j) { acc1[i][j] = (f32x4)0.f; acc2[i][j] = (f32x4)0.f; } \
    const __bf16* Abase = enc_bf + ((size_t)b * TS + t0) * VDIM;                    \
    const int sm = tid >> 2;                                                        \
    const int sj = (tid & 3) ^ (sm & 3) ^ ((sm >> 2) & 3);                          \
    const __bf16* gpA = Abase + (size_t)sm * VDIM + sj * 8;                         \
    const __bf16* gp1 = (B1ptr) + ((size_t)n0 + sm) * VDIM + sj * 8;                \
    const __bf16* gp2 = (B2ptr) + ((size_t)n0 + sm) * VDIM + sj * 8;                \
    const int cfr = quad ^ (col & 3) ^ ((col >> 2) & 3);                            \
    const char* pA = (const char*)Ash  + (((wy * 64 + col) * 4 + cfr) << 4);        \
    const char* p1 = (const char*)B1sh + (((wx * 32 + col) * 4 + cfr) << 4);        \
    const char* p2 = (const char*)B2sh + (((wx * 32 + col) * 4 + cfr) << 4);        \
    __builtin_amdgcn_global_load_lds(AS1(gpA), AS3(Ash + w * 512), 16, 0, 0);       \
    __builtin_amdgcn_global_load_lds(AS1(gp1), AS3(B1sh + w * 512), 16, 0, 0);      \
    if (DOV) __builtin_amdgcn_global_load_lds(AS1(gp2), AS3(B2sh + w * 512), 16, 0, 0); \
    gpA += 32; gp1 += 32; gp2 += 32;                                                \
    for (int kk = 0; kk < 16; ++kk) {                                               \
        __syncthreads();                                                            \
        if (kk < 15) {                                                              \
            int nb = ((kk + 1) & 1) * 4096;                                         \
            __builtin_amdgcn_global_load_lds(AS1(gpA), AS3(Ash + nb + w * 512), 16, 0, 0);  \
            __builtin_amdgcn_global_load_lds(AS1(gp1), AS3(B1sh + nb + w * 512), 16, 0, 0); \
            if (DOV) __builtin_amdgcn_global_load_lds(AS1(gp2), AS3(B2sh + nb + w * 512), 16, 0, 0); \
            gpA += 32; gp1 += 32; gp2 += 32;                                        \
        }                                                                           \
        const int bo = (kk & 1) * 8192;                                             \
        bf16x8 af[4], f1[2], f2[2];                                                 \
        _Pragma("unroll")                                                           \
        for (int i = 0; i < 4; ++i) af[i] = *(const bf16x8*)(pA + bo + i * 1024);   \
        _Pragma("unroll")                                                           \
        for (int j = 0; j < 2; ++j) f1[j] = *(const bf16x8*)(p1 + bo + j * 1024);   \
        if (DOV) {                                                                  \
            _Pragma("unroll")                                                       \
            for (int j = 0; j < 2; ++j) f2[j] = *(const bf16x8*)(p2 + bo + j * 1024); \
        }                                                                           \
        _Pragma("unroll")                                                           \
        for (int i = 0; i < 4; ++i) {                                               \
            _Pragma("unroll")                                                       \
            for (int j = 0; j < 2; ++j) {                                           \
                acc1[i][j] = __builtin_amdgcn_mfma_f32_16x16x32_bf16(               \
                    af[i], f1[j], acc1[i][j], 0, 0, 0);                             \
                if (DOV) acc2[i][j] = __builtin_amdgcn_mfma_f32_16x16x32_bf16(      \
                    af[i], f2[j], acc2[i][j], 0, 0, 0);                             \
            }                                                                       \
        }                                                                           \
    }                                                                               \
    __syncthreads();
// acc*[i][j][r] = C[t0+wy*64+i*16+quad*4+r][n0+wx*32+j*16+col]

// ---------------------------------------------------------------------------
// Fused pass: acc1 = enc @ Wk^T  (energy epilogue), acc2 = enc @ Wv^T
// (value = tanh(acc2+bv) stored bf16, only if WITHV)
// ---------------------------------------------------------------------------
template<bool WITHV>
__global__ __launch_bounds__(512, 4) void k_fused(
    const __bf16* __restrict__ enc_bf, const __bf16* __restrict__ wk_bf,
    const __bf16* __restrict__ wv_bf, const float* __restrict__ bk,
    const float* __restrict__ bv, const float* __restrict__ gen_w,
    const int* __restrict__ enc_len, const float* __restrict__ query,
    const float* __restrict__ Qtab, const float* __restrict__ locI,
    float* __restrict__ energy, __bf16* __restrict__ value) {
    GEMM32(wk_bf, wv_bf, WITHV)

    const int h = n0 >> 9;
    const float inv_len = 1.0f / (float)len;
    float qv[2], gw[2], bkv[2], lI[2], bvv[2];
    int dj[2];
    #pragma unroll
    for (int j = 0; j < 2; ++j) {
        int n = n0 + wx * 32 + j * 16 + col;
        dj[j] = n & (DIM - 1);
        qv[j] = query[b * NHD + n];
        gw[j] = gen_w[dj[j]];
        bkv[j] = bk[n];
        lI[j] = locI[b * DIM + dj[j]];
        bvv[j] = WITHV ? bv[n] : 0.f;
    }
    __bf16* vb = WITHV ? (value + ((size_t)(b * NH + h) * TS) * VDIM) : nullptr;
    float* red = (float*)Ash;   // [128][4]
    #pragma unroll
    for (int i = 0; i < 4; ++i) {
        #pragma unroll
        for (int r = 0; r < 4; ++r) {
            int tl = wy * 64 + i * 16 + quad * 4 + r;
            int t = t0 + tl;
            float l[2];
            if (t >= KS && t < len - KS) {           // interior: loc const in t
                #pragma unroll
                for (int j = 0; j < 2; ++j) l[j] = lI[j];
            } else {
                int lo = KS - t; if (lo < 0) lo = 0;
                int hi = KS - t + len - 1; if (hi > 2 * KS) hi = 2 * KS;
                bool has = (hi >= lo);
                #pragma unroll
                for (int j = 0; j < 2; ++j) {
                    float cv = has
                        ? (Qtab[(hi + 1) * DIM + dj[j]] - Qtab[lo * DIM + dj[j]]) * inv_len
                        : 0.f;
                    l[j] = fast_tanh(cv);
                }
            }
            float s = 0.f;
            #pragma unroll
            for (int j = 0; j < 2; ++j) {
                float key = fast_tanh(acc1[i][j][r] + bkv[j]);
                float e = fast_tanh(key + qv[j] + l[j]);
                s = fmaf(e, gw[j], s);
                if (WITHV)
                    vb[(size_t)t * VDIM + dj[j]] =
                        (__bf16)fast_tanh(acc2[i][j][r] + bvv[j]);
            }
            s += __shfl_xor(s, 1); s += __shfl_xor(s, 2);
            s += __shfl_xor(s, 4); s += __shfl_xor(s, 8);
            if (col == 0) red[tl * 4 + wx] = s;
        }
    }
    __syncthreads();
    if (tid < 128) {
        float s = red[tid * 4] + red[tid * 4 + 1] + red[tid * 4 + 2] + red[tid * 4 + 3];
        atomicAdd(&energy[(size_t)(b * NH + h) * TS + t0 + tid], s);
    }
}

// ---------------------------------------------------------------------------
// ctx[b,h,dv] = sum_t attn[b,h,t] * value[b,h,t,dv]   (memory-bound)
// grid (TS/128, NH, BS) x 512 threads; tid = dv
// ---------------------------------------------------------------------------
__global__ void k_ctxv(const __bf16* __restrict__ value, const float* __restrict__ attn,
                       const int* __restrict__ enc_len, float* __restrict__ ctx) {
    const int tc = blockIdx.x * 128;
    const int h = blockIdx.y, b = blockIdx.z;
    if (tc >= enc_len[b]) return;
    const int bh = b * NH + h;
    const __bf16* vbase = value + ((size_t)bh * TS + tc) * VDIM + threadIdx.x;
    const float* abase = attn + (size_t)bh * TS + tc;
    float s = 0.f;
    #pragma unroll 8
    for (int t = 0; t < 128; ++t)
        s = fmaf(abase[t], (float)vbase[(size_t)t * VDIM], s);
    atomicAdd(&ctx[(size_t)b * NHD + h * VDIM + threadIdx.x], s);
}

// ---------------------------------------------------------------------------
// Fallback ctx pass (small ws): C = enc @ Wv^T, ctx += sum_t attn*tanh(C+bv)
// ---------------------------------------------------------------------------
__global__ __launch_bounds__(512, 4) void k_ctxg(
    const __bf16* __restrict__ enc_bf, const __bf16* __restrict__ wv_bf,
    const float* __restrict__ bv, const float* __restrict__ attn,
    const int* __restrict__ enc_len, float* __restrict__ ctx) {
    GEMM32(wv_bf, wv_bf, 0)

    const int h = n0 >> 9;
    float att[4][4];
    #pragma unroll
    for (int i = 0; i < 4; ++i)
        #pragma unroll
        for (int r = 0; r < 4; ++r)
            att[i][r] = attn[(size_t)(b * NH + h) * TS + t0 + wy * 64 + i * 16 + quad * 4 + r];
    float* red = (float*)Ash;   // [128][2]
    #pragma unroll
    for (int j = 0; j < 2; ++j) {
        int nl = wx * 32 + j * 16 + col;
        float bvn = bv[n0 + nl];
        float s = 0.f;
        #pragma unroll
        for (int i = 0; i < 4; ++i)
            #pragma unroll
            for (int r = 0; r < 4; ++r)
                s = fmaf(att[i][r], fast_tanh(acc1[i][j][r] + bvn), s);
        s += __shfl_xor(s, 16); s += __shfl_xor(s, 32);
        if (quad == 0) red[nl * 2 + wy] = s;
    }
    __syncthreads();
    if (tid < 128) {
        float s = red[tid * 2] + red[tid * 2 + 1];
        atomicAdd(&ctx[(size_t)b * NHD + n0 + tid], s);
    }
}

// ---------------------------------------------------------------------------
// softmax over t (masked), shuffle-based, writes attn to d_out
// ---------------------------------------------------------------------------
__global__ void k_softmax(const float* __restrict__ energy, const int* __restrict__ enc_len,
                          const float* __restrict__ gen_b, float* __restrict__ attn) {
    int bh = blockIdx.x;          // 32
    int b = bh >> 2;
    int len = enc_len[b];
    int tid = threadIdx.x;        // 512
    int w = tid >> 6, lane = tid & 63;
    const float gb = gen_b[0];
    float ev[4];
    float mx = -INFINITY;
    #pragma unroll
    for (int i = 0; i < 4; ++i) {
        int t = i * 512 + tid;
        float e = (t < len) ? (energy[(size_t)bh * TS + t] + gb) * (1.0f / TEMPERATURE)
                            : -INFINITY;
        ev[i] = e;
        mx = fmaxf(mx, e);
    }
    __shared__ float sred[8], ssum[8];
    #pragma unroll
    for (int off = 32; off > 0; off >>= 1) mx = fmaxf(mx, __shfl_xor(mx, off));
    if (lane == 0) sred[w] = mx;
    __syncthreads();
    #pragma unroll
    for (int k = 0; k < 8; ++k) mx = fmaxf(mx, sred[k]);
    float ls = 0.f;
    #pragma unroll
    for (int i = 0; i < 4; ++i) {
        float ex = __expf(ev[i] - mx);
        ev[i] = ex;
        ls += ex;
    }
    #pragma unroll
    for (int off = 32; off > 0; off >>= 1) ls += __shfl_xor(ls, off);
    if (lane == 0) ssum[w] = ls;
    __syncthreads();
    float tot = 0.f;
    #pragma unroll
    for (int k = 0; k < 8; ++k) tot += ssum[k];
    float inv = 1.0f / tot;
    #pragma unroll
    for (int i = 0; i < 4; ++i)
        attn[(size_t)bh * TS + i * 512 + tid] = ev[i] * inv;
}

// ---------------------------------------------------------------------------
// context[b,o] = ctx[b,:] . merge_w[o,:] + merge_b[o];  one wave per output
// ---------------------------------------------------------------------------
__global__ void k_merge(const float* __restrict__ ctx, const float* __restrict__ mw,
                        const float* __restrict__ mb, float* __restrict__ out) {
    int w = (blockIdx.x * blockDim.x + threadIdx.x) >> 6;
    int lane = threadIdx.x & 63;
    int b = w >> 9;
    int o = w & 511;
    const float* c = ctx + (size_t)b * NHD;
    const float* wr = mw + (size_t)o * NHD;
    float s = 0.f;
    #pragma unroll
    for (int i = 0; i < NHD / 64; ++i) s = fmaf(c[lane + 64 * i], wr[lane + 64 * i], s);
    #pragma unroll
    for (int off = 32; off > 0; off >>= 1) s += __shfl_down(s, off);
    if (lane == 0) out[b * VDIM + o] = s + mb[o];
}

extern "C" void kernel_launch(void* const* d_in, const int* in_sizes, int n_in,
                              void* d_out, int out_size, void* d_ws, size_t ws_size,
                              hipStream_t stream) {
    const float* dec     = (const float*)d_in[0];
    const float* enc     = (const float*)d_in[1];
    const int*   enc_len = (const int*)d_in[2];
    const float* Wq      = (const float*)d_in[3];
    const float* bq      = (const float*)d_in[4];
    const float* Wk      = (const float*)d_in[5];
    const float* bk      = (const float*)d_in[6];
    const float* Wv      = (const float*)d_in[7];
    const float* bv      = (const float*)d_in[8];
    const float* convw   = (const float*)d_in[9];
    const float* projw   = (const float*)d_in[10];
    const float* gen_w   = (const float*)d_in[11];
    const float* gen_b   = (const float*)d_in[12];
    const float* merge_w = (const float*)d_in[13];
    const float* merge_b = (const float*)d_in[14];

    float* out   = (float*)d_out;               // attn [65536] ++ context [4096]
    float* ws    = (float*)d_ws;
    float* query = ws + WS_QUERY;
    float* Qtab  = ws + WS_QTAB;
    float* energy= ws + WS_ENERGY;
    float* ctx   = ws + WS_CTX;
    float* locI  = ws + WS_LOCI;
    float* Pws   = ws + WS_P;
    __bf16* enc_bf = (__bf16*)((char*)d_ws + (size_t)WS_F32_END * 4);
    __bf16* wk_bf  = enc_bf + (size_t)BS * TS * VDIM;
    __bf16* wv_bf  = wk_bf + (size_t)NHD * VDIM;
    __bf16* value  = wv_bf + (size_t)NHD * VDIM;
    const bool big = ws_size >= WS_NEED_BIG;

    // zero atomic accumulators (energy + ctx contiguous)
    hipMemsetAsync(energy, 0, (65536 + 16384) * sizeof(float), stream);

    k_cvt3<<<dim3((NE4 + 2 * NW4) / 256), dim3(256), 0, stream>>>(
        enc, Wk, Wv, enc_bf, wk_bf, wv_bf);
    k_query<<<dim3(BS * NHD / 4), dim3(256), 0, stream>>>(dec, Wq, bq, query);
    k_prefix<<<dim3(1), dim3(128), 0, stream>>>(convw, Pws);
    k_qtab<<<dim3(2 * KS + 2), dim3(512), 0, stream>>>(Pws, projw, Qtab);
    k_locI<<<dim3(BS * DIM / 256), dim3(256), 0, stream>>>(Qtab, enc_len, locI);
    if (big) {
        k_fused<true><<<dim3(TS / 128, NHD / 128, BS), dim3(512), 0, stream>>>(
            enc_bf, wk_bf, wv_bf, bk, bv, gen_w, enc_len, query, Qtab, locI,
            energy, value);
        k_softmax<<<dim3(BS * NH), dim3(512), 0, stream>>>(energy, enc_len, gen_b, out);
        k_ctxv<<<dim3(TS / 128, NH, BS), dim3(512), 0, stream>>>(
            value, out, enc_len, ctx);
    } else {
        k_fused<false><<<dim3(TS / 128, NHD / 128, BS), dim3(512), 0, stream>>>(
            enc_bf, wk_bf, wv_bf, bk, bv, gen_w, enc_len, query, Qtab, locI,
            energy, nullptr);
        k_softmax<<<dim3(BS * NH), dim3(512), 0, stream>>>(energy, enc_len, gen_b, out);
        k_ctxg<<<dim3(TS / 128, NHD / 128, BS), dim3(512), 0, stream>>>(
            enc_bf, wv_bf, bv, out, enc_len, ctx);
    }
    k_merge<<<dim3(BS * VDIM / 4), dim3(256), 0, stream>>>(ctx, merge_w, merge_b, out + 65536);
}

// Round 7
// 359.363 us; speedup vs baseline: 1.0448x; 1.0448x over previous
//
#include <hip/hip_runtime.h>
#include <math.h>

#define NH 4
#define DIM 512
#define VDIM 512
#define QDIM 1024
#define KS 100
#define KN 100
#define TEMPERATURE 0.5f
#define BS 8
#define TS 2048
#define NHD (NH * DIM)          // 2048

// workspace layout (floats)
#define WS_QUERY  0                       // 16384
#define WS_QTAB   16384                   // 202*512 = 103424
#define WS_ENERGY 119808                  // 65536
#define WS_CTX    185344                  // 16384
#define WS_LOCI   201728                  // 8*512 = 4096
#define WS_P      205824                  // 202*100 = 20200
#define WS_F32_END 226028                 // *4 bytes
// bf16 region: enc_bf [8388608 el], wk_bf [1048576], wv_bf [1048576],
//              value [33554432 el] (blocked layout; only if ws_size allows)
#define WS_NEED_BIG (WS_F32_END * 4ull + 2ull * (8388608 + 1048576 + 1048576 + 33554432))

typedef __bf16 bf16x8 __attribute__((ext_vector_type(8)));
typedef __bf16 bf16x4 __attribute__((ext_vector_type(4)));
typedef float  f32x4  __attribute__((ext_vector_type(4)));

#define AS1(p) ((const __attribute__((address_space(1))) void*)(p))
#define AS3(p) ((__attribute__((address_space(3))) void*)(p))

__device__ __forceinline__ float fast_tanh(float x) {
    float xc = fminf(fmaxf(x, -9.0f), 9.0f);
    float e = __expf(2.0f * xc);
    return __fdividef(e - 1.0f, e + 1.0f);
}

// ---------------------------------------------------------------------------
// merged: fp32->bf16 conversion (3 tensors) + query GEMV, one dispatch
// ---------------------------------------------------------------------------
#define NE4 (BS * TS * VDIM / 4)      // 2097152
#define NW4 (NHD * VDIM / 4)          // 262144
#define NCVT ((NE4 + 2 * NW4) / 256)  // 10240 cvt blocks
__global__ void k_precvt(const float* __restrict__ enc, const float* __restrict__ Wk,
                         const float* __restrict__ Wv, __bf16* __restrict__ enc_bf,
                         __bf16* __restrict__ wk_bf, __bf16* __restrict__ wv_bf,
                         const float* __restrict__ dec, const float* __restrict__ Wq,
                         const float* __restrict__ bq, float* __restrict__ query) {
    if (blockIdx.x < NCVT) {
        int i = blockIdx.x * blockDim.x + threadIdx.x;
        const float* src; __bf16* dst; int k;
        if (i < NE4)            { src = enc; dst = enc_bf; k = i; }
        else if (i < NE4 + NW4) { src = Wk;  dst = wk_bf;  k = i - NE4; }
        else                    { src = Wv;  dst = wv_bf;  k = i - NE4 - NW4; }
        float4 v = ((const float4*)src)[k];
        bf16x4 o;
        o[0] = (__bf16)v.x; o[1] = (__bf16)v.y; o[2] = (__bf16)v.z; o[3] = (__bf16)v.w;
        ((bf16x4*)dst)[k] = o;
    } else {
        int q = blockIdx.x - NCVT;                       // 0..4095
        int w = q * 4 + (threadIdx.x >> 6);              // wave id = output id
        int lane = threadIdx.x & 63;
        int b = w >> 11;
        int o = w & 2047;
        const float* dr = dec + b * QDIM;
        const float* wr = Wq + o * QDIM;
        float s = 0.f;
        #pragma unroll
        for (int i = 0; i < QDIM / 64; ++i)
            s = fmaf(dr[lane + 64 * i], wr[lane + 64 * i], s);
        #pragma unroll
        for (int off = 32; off > 0; off >>= 1) s += __shfl_down(s, off);
        if (lane == 0) query[b * NHD + o] = tanhf(s + bq[o]);
    }
}

// ---------------------------------------------------------------------------
// P[j][k] = sum_{dt<j} sum_h convw[k,h,dt]  -- one linear sweep per k.
// ---------------------------------------------------------------------------
__global__ void k_prefix(const float* __restrict__ convw, float* __restrict__ P) {
    int k = threadIdx.x;
    if (k >= KN) return;
    const float* wr = convw + k * (NH * (2 * KS + 1));
    float acc = 0.f;
    P[k] = 0.f;
    for (int dt = 0; dt < 2 * KS + 1; ++dt) {
        acc += wr[dt] + wr[201 + dt] + wr[402 + dt] + wr[603 + dt];
        P[(dt + 1) * KN + k] = acc;
    }
}

// ---------------------------------------------------------------------------
// Qtab[j,d] = sum_k projw[d,k] * P[j,k]
// ---------------------------------------------------------------------------
__global__ void k_qtab(const float* __restrict__ P, const float* __restrict__ projw,
                       float* __restrict__ Qtab) {
    int j = blockIdx.x;       // 0..201
    __shared__ float Pc[KN];
    int tid = threadIdx.x;    // 512
    if (tid < KN) Pc[tid] = P[j * KN + tid];
    __syncthreads();
    const float* pr = projw + tid * KN;
    float s = 0.f;
    #pragma unroll 4
    for (int k = 0; k < KN; ++k) s = fmaf(pr[k], Pc[k], s);
    Qtab[j * DIM + tid] = s;
}

// ---------------------------------------------------------------------------
// locI[b,d] = tanh((Qtab[2KS+1,d]-Qtab[0,d])/len_b)  (interior-t loc value)
// ---------------------------------------------------------------------------
__global__ void k_locI(const float* __restrict__ Qtab, const int* __restrict__ enc_len,
                       float* __restrict__ locI) {
    int idx = blockIdx.x * blockDim.x + threadIdx.x;   // BS*DIM
    int b = idx >> 9, d = idx & (DIM - 1);
    float inv_len = 1.0f / (float)enc_len[b];
    locI[idx] = fast_tanh((Qtab[(2 * KS + 1) * DIM + d] - Qtab[d]) * inv_len);
}

// ===========================================================================
// GEMM core: 128x128 tile, BK=32, 512 threads (8 waves, 2x4 grid, wave tile
// 64x32), double-buffered LDS, one barrier/iter, loop-invariant addresses.
// Swizzle: phys chunk c = j ^ (m&3) ^ ((m>>2)&3).
// ===========================================================================
#define GEMM32(B1ptr, B2ptr, DOV)                                                  \
    const int t0 = blockIdx.x * 128;                                                \
    const int n0 = blockIdx.y * 128;                                                \
    const int b  = blockIdx.z;                                                      \
    const int len = enc_len[b];                                                     \
    if (t0 >= len) return;                                                          \
    const int tid = threadIdx.x;                                                    \
    const int w = tid >> 6, lane = tid & 63;                                        \
    const int wy = w >> 2, wx = w & 3;                                              \
    const int col = lane & 15, quad = lane >> 4;                                    \
    __shared__ __bf16 Ash[2 * 4096];                                                \
    __shared__ __bf16 B1sh[2 * 4096];                                               \
    __shared__ __bf16 B2sh[2 * 4096];                                               \
    f32x4 acc1[4][2], acc2[4][2];                                                   \
    _Pragma("unroll")                                                               \
    for (int i = 0; i < 4; ++i)                                                     \
        _Pragma("unroll")                                                           \
        for (int j = 0; j < 2; ++j) { acc1[i][j] = (f32x4)0.f; acc2[i][j] = (f32x4)0.f; } \
    const __bf16* Abase = enc_bf + ((size_t)b * TS + t0) * VDIM;                    \
    const int sm = tid >> 2;                                                        \
    const int sj = (tid & 3) ^ (sm & 3) ^ ((sm >> 2) & 3);                          \
    const __bf16* gpA = Abase + (size_t)sm * VDIM + sj * 8;                         \
    const __bf16* gp1 = (B1ptr) + ((size_t)n0 + sm) * VDIM + sj * 8;                \
    const __bf16* gp2 = (B2ptr) + ((size_t)n0 + sm) * VDIM + sj * 8;                \
    const int cfr = quad ^ (col & 3) ^ ((col >> 2) & 3);                            \
    const char* pA = (const char*)Ash  + (((wy * 64 + col) * 4 + cfr) << 4);        \
    const char* p1 = (const char*)B1sh + (((wx * 32 + col) * 4 + cfr) << 4);        \
    const char* p2 = (const char*)B2sh + (((wx * 32 + col) * 4 + cfr) << 4);        \
    __builtin_amdgcn_global_load_lds(AS1(gpA), AS3(Ash + w * 512), 16, 0, 0);       \
    __builtin_amdgcn_global_load_lds(AS1(gp1), AS3(B1sh + w * 512), 16, 0, 0);      \
    if (DOV) __builtin_amdgcn_global_load_lds(AS1(gp2), AS3(B2sh + w * 512), 16, 0, 0); \
    gpA += 32; gp1 += 32; gp2 += 32;                                                \
    for (int kk = 0; kk < 16; ++kk) {                                               \
        __syncthreads();                                                            \
        if (kk < 15) {                                                              \
            int nb_ = ((kk + 1) & 1) * 4096;                                        \
            __builtin_amdgcn_global_load_lds(AS1(gpA), AS3(Ash + nb_ + w * 512), 16, 0, 0);  \
            __builtin_amdgcn_global_load_lds(AS1(gp1), AS3(B1sh + nb_ + w * 512), 16, 0, 0); \
            if (DOV) __builtin_amdgcn_global_load_lds(AS1(gp2), AS3(B2sh + nb_ + w * 512), 16, 0, 0); \
            gpA += 32; gp1 += 32; gp2 += 32;                                        \
        }                                                                           \
        const int bo = (kk & 1) * 8192;                                             \
        bf16x8 af[4], f1[2], f2[2];                                                 \
        _Pragma("unroll")                                                           \
        for (int i = 0; i < 4; ++i) af[i] = *(const bf16x8*)(pA + bo + i * 1024);   \
        _Pragma("unroll")                                                           \
        for (int j = 0; j < 2; ++j) f1[j] = *(const bf16x8*)(p1 + bo + j * 1024);   \
        if (DOV) {                                                                  \
            _Pragma("unroll")                                                       \
            for (int j = 0; j < 2; ++j) f2[j] = *(const bf16x8*)(p2 + bo + j * 1024); \
        }                                                                           \
        _Pragma("unroll")                                                           \
        for (int i = 0; i < 4; ++i) {                                               \
            _Pragma("unroll")                                                       \
            for (int j = 0; j < 2; ++j) {                                           \
                acc1[i][j] = __builtin_amdgcn_mfma_f32_16x16x32_bf16(               \
                    af[i], f1[j], acc1[i][j], 0, 0, 0);                             \
                if (DOV) acc2[i][j] = __builtin_amdgcn_mfma_f32_16x16x32_bf16(      \
                    af[i], f2[j], acc2[i][j], 0, 0, 0);                             \
            }                                                                       \
        }                                                                           \
    }                                                                               \
    __syncthreads();
// acc*[i][j][r] = C[t0+wy*64+i*16+quad*4+r][n0+wx*32+j*16+col]

// ---------------------------------------------------------------------------
// Fused pass: acc1 = enc @ Wk^T  (energy epilogue), acc2 = enc @ Wv^T.
// value = tanh(acc2+bv) stored bf16 in BLOCKED fragment-order layout:
//   vblk[(b*16+nb)*16+tb][plane=i*2+j][tid][r]  -- 8B/thread coalesced.
// ---------------------------------------------------------------------------
template<bool WITHV>
__global__ __launch_bounds__(512, 4) void k_fused(
    const __bf16* __restrict__ enc_bf, const __bf16* __restrict__ wk_bf,
    const __bf16* __restrict__ wv_bf, const float* __restrict__ bk,
    const float* __restrict__ bv, const float* __restrict__ gen_w,
    const int* __restrict__ enc_len, const float* __restrict__ query,
    const float* __restrict__ Qtab, const float* __restrict__ locI,
    float* __restrict__ energy, __bf16* __restrict__ value) {
    GEMM32(wk_bf, wv_bf, WITHV)

    const int h = n0 >> 9;
    const float inv_len = 1.0f / (float)len;
    float qv[2], gw[2], bkv[2], lI[2], bvv[2];
    int dj[2];
    #pragma unroll
    for (int j = 0; j < 2; ++j) {
        int n = n0 + wx * 32 + j * 16 + col;
        dj[j] = n & (DIM - 1);
        qv[j] = query[b * NHD + n];
        gw[j] = gen_w[dj[j]];
        bkv[j] = bk[n];
        lI[j] = locI[b * DIM + dj[j]];
        bvv[j] = WITHV ? bv[n] : 0.f;
    }
    // ---- value: blocked coalesced store ----
    if (WITHV) {
        __bf16* vb = value +
            (((size_t)b * 16 + (n0 >> 7)) * 16 + (t0 >> 7)) * 16384 + tid * 4;
        #pragma unroll
        for (int i = 0; i < 4; ++i) {
            #pragma unroll
            for (int j = 0; j < 2; ++j) {
                bf16x4 v;
                #pragma unroll
                for (int r = 0; r < 4; ++r)
                    v[r] = (__bf16)fast_tanh(acc2[i][j][r] + bvv[j]);
                *(bf16x4*)(vb + (i * 2 + j) * 2048) = v;
            }
        }
    }
    // ---- energy epilogue ----
    float* red = (float*)Ash;   // [128][4]
    #pragma unroll
    for (int i = 0; i < 4; ++i) {
        #pragma unroll
        for (int r = 0; r < 4; ++r) {
            int tl = wy * 64 + i * 16 + quad * 4 + r;
            int t = t0 + tl;
            float l[2];
            if (t >= KS && t < len - KS) {           // interior: loc const in t
                #pragma unroll
                for (int j = 0; j < 2; ++j) l[j] = lI[j];
            } else {
                int lo = KS - t; if (lo < 0) lo = 0;
                int hi = KS - t + len - 1; if (hi > 2 * KS) hi = 2 * KS;
                bool has = (hi >= lo);
                #pragma unroll
                for (int j = 0; j < 2; ++j) {
                    float cv = has
                        ? (Qtab[(hi + 1) * DIM + dj[j]] - Qtab[lo * DIM + dj[j]]) * inv_len
                        : 0.f;
                    l[j] = fast_tanh(cv);
                }
            }
            float s = 0.f;
            #pragma unroll
            for (int j = 0; j < 2; ++j) {
                float key = fast_tanh(acc1[i][j][r] + bkv[j]);
                float e = fast_tanh(key + qv[j] + l[j]);
                s = fmaf(e, gw[j], s);
            }
            s += __shfl_xor(s, 1); s += __shfl_xor(s, 2);
            s += __shfl_xor(s, 4); s += __shfl_xor(s, 8);
            if (col == 0) red[tl * 4 + wx] = s;
        }
    }
    __syncthreads();
    if (tid < 128) {
        float s = red[tid * 4] + red[tid * 4 + 1] + red[tid * 4 + 2] + red[tid * 4 + 3];
        atomicAdd(&energy[(size_t)(b * NH + h) * TS + t0 + tid], s);
    }
}

// ---------------------------------------------------------------------------
// ctx from blocked value: grid (16 nb, 8 b) x 512; same (w,lane) geometry as
// the producer. No atomics: each block owns its 128 ctx outputs.
// ---------------------------------------------------------------------------
__global__ __launch_bounds__(512) void k_ctxv(
    const __bf16* __restrict__ value, const float* __restrict__ attn,
    const int* __restrict__ enc_len, float* __restrict__ ctx) {
    const int nb = blockIdx.x;     // 0..15 over NHD/128
    const int b  = blockIdx.y;
    const int len = enc_len[b];
    const int tid = threadIdx.x;
    const int w = tid >> 6, lane = tid & 63;
    const int wy = w >> 2, wx = w & 3;
    const int col = lane & 15, quad = lane >> 4;
    const int h = nb >> 2;
    const float* arow = attn + (size_t)(b * NH + h) * TS;
    float s0 = 0.f, s1 = 0.f;
    for (int tb = 0; tb < 16; ++tb) {
        if (tb * 128 >= len) break;
        const __bf16* base = value +
            (((size_t)b * 16 + nb) * 16 + tb) * 16384 + tid * 4;
        #pragma unroll
        for (int i = 0; i < 4; ++i) {
            int t = tb * 128 + wy * 64 + i * 16 + quad * 4;
            float a0 = arow[t], a1 = arow[t + 1], a2 = arow[t + 2], a3 = arow[t + 3];
            bf16x4 v0 = *(const bf16x4*)(base + (i * 2 + 0) * 2048);
            bf16x4 v1 = *(const bf16x4*)(base + (i * 2 + 1) * 2048);
            s0 += a0 * (float)v0[0] + a1 * (float)v0[1] + a2 * (float)v0[2] + a3 * (float)v0[3];
            s1 += a0 * (float)v1[0] + a1 * (float)v1[1] + a2 * (float)v1[2] + a3 * (float)v1[3];
        }
    }
    s0 += __shfl_xor(s0, 16); s0 += __shfl_xor(s0, 32);
    s1 += __shfl_xor(s1, 16); s1 += __shfl_xor(s1, 32);
    __shared__ float red[128][2];
    if (quad == 0) {
        red[wx * 32 + col][wy] = s0;
        red[wx * 32 + 16 + col][wy] = s1;
    }
    __syncthreads();
    if (tid < 128)
        ctx[(size_t)b * NHD + nb * 128 + tid] = red[tid][0] + red[tid][1];
}

// ---------------------------------------------------------------------------
// Fallback ctx pass (small ws): C = enc @ Wv^T, ctx += sum_t attn*tanh(C+bv)
// ---------------------------------------------------------------------------
__global__ __launch_bounds__(512, 4) void k_ctxg(
    const __bf16* __restrict__ enc_bf, const __bf16* __restrict__ wv_bf,
    const float* __restrict__ bv, const float* __restrict__ attn,
    const int* __restrict__ enc_len, float* __restrict__ ctx) {
    GEMM32(wv_bf, wv_bf, 0)

    const int h = n0 >> 9;
    float att[4][4];
    #pragma unroll
    for (int i = 0; i < 4; ++i)
        #pragma unroll
        for (int r = 0; r < 4; ++r)
            att[i][r] = attn[(size_t)(b * NH + h) * TS + t0 + wy * 64 + i * 16 + quad * 4 + r];
    float* red = (float*)Ash;   // [128][2]
    #pragma unroll
    for (int j = 0; j < 2; ++j) {
        int nl = wx * 32 + j * 16 + col;
        float bvn = bv[n0 + nl];
        float s = 0.f;
        #pragma unroll
        for (int i = 0; i < 4; ++i)
            #pragma unroll
            for (int r = 0; r < 4; ++r)
                s = fmaf(att[i][r], fast_tanh(acc1[i][j][r] + bvn), s);
        s += __shfl_xor(s, 16); s += __shfl_xor(s, 32);
        if (quad == 0) red[nl * 2 + wy] = s;
    }
    __syncthreads();
    if (tid < 128) {
        float s = red[tid * 2] + red[tid * 2 + 1];
        atomicAdd(&ctx[(size_t)b * NHD + n0 + tid], s);
    }
}

// ---------------------------------------------------------------------------
// softmax over t (masked), shuffle-based, writes attn to d_out
// ---------------------------------------------------------------------------
__global__ void k_softmax(const float* __restrict__ energy, const int* __restrict__ enc_len,
                          const float* __restrict__ gen_b, float* __restrict__ attn) {
    int bh = blockIdx.x;          // 32
    int b = bh >> 2;
    int len = enc_len[b];
    int tid = threadIdx.x;        // 512
    int w = tid >> 6, lane = tid & 63;
    const float gb = gen_b[0];
    float ev[4];
    float mx = -INFINITY;
    #pragma unroll
    for (int i = 0; i < 4; ++i) {
        int t = i * 512 + tid;
        float e = (t < len) ? (energy[(size_t)bh * TS + t] + gb) * (1.0f / TEMPERATURE)
                            : -INFINITY;
        ev[i] = e;
        mx = fmaxf(mx, e);
    }
    __shared__ float sred[8], ssum[8];
    #pragma unroll
    for (int off = 32; off > 0; off >>= 1) mx = fmaxf(mx, __shfl_xor(mx, off));
    if (lane == 0) sred[w] = mx;
    __syncthreads();
    #pragma unroll
    for (int k = 0; k < 8; ++k) mx = fmaxf(mx, sred[k]);
    float ls = 0.f;
    #pragma unroll
    for (int i = 0; i < 4; ++i) {
        float ex = __expf(ev[i] - mx);
        ev[i] = ex;
        ls += ex;
    }
    #pragma unroll
    for (int off = 32; off > 0; off >>= 1) ls += __shfl_xor(ls, off);
    if (lane == 0) ssum[w] = ls;
    __syncthreads();
    float tot = 0.f;
    #pragma unroll
    for (int k = 0; k < 8; ++k) tot += ssum[k];
    float inv = 1.0f / tot;
    #pragma unroll
    for (int i = 0; i < 4; ++i)
        attn[(size_t)bh * TS + i * 512 + tid] = ev[i] * inv;
}

// ---------------------------------------------------------------------------
// context[b,o] = ctx[b,:] . merge_w[o,:] + merge_b[o];  one wave per output
// ---------------------------------------------------------------------------
__global__ void k_merge(const float* __restrict__ ctx, const float* __restrict__ mw,
                        const float* __restrict__ mb, float* __restrict__ out) {
    int w = (blockIdx.x * blockDim.x + threadIdx.x) >> 6;
    int lane = threadIdx.x & 63;
    int b = w >> 9;
    int o = w & 511;
    const float* c = ctx + (size_t)b * NHD;
    const float* wr = mw + (size_t)o * NHD;
    float s = 0.f;
    #pragma unroll
    for (int i = 0; i < NHD / 64; ++i) s = fmaf(c[lane + 64 * i], wr[lane + 64 * i], s);
    #pragma unroll
    for (int off = 32; off > 0; off >>= 1) s += __shfl_down(s, off);
    if (lane == 0) out[b * VDIM + o] = s + mb[o];
}

extern "C" void kernel_launch(void* const* d_in, const int* in_sizes, int n_in,
                              void* d_out, int out_size, void* d_ws, size_t ws_size,
                              hipStream_t stream) {
    const float* dec     = (const float*)d_in[0];
    const float* enc     = (const float*)d_in[1];
    const int*   enc_len = (const int*)d_in[2];
    const float* Wq      = (const float*)d_in[3];
    const float* bq      = (const float*)d_in[4];
    const float* Wk      = (const float*)d_in[5];
    const float* bk      = (const float*)d_in[6];
    const float* Wv      = (const float*)d_in[7];
    const float* bv      = (const float*)d_in[8];
    const float* convw   = (const float*)d_in[9];
    const float* projw   = (const float*)d_in[10];
    const float* gen_w   = (const float*)d_in[11];
    const float* gen_b   = (const float*)d_in[12];
    const float* merge_w = (const float*)d_in[13];
    const float* merge_b = (const float*)d_in[14];

    float* out   = (float*)d_out;               // attn [65536] ++ context [4096]
    float* ws    = (float*)d_ws;
    float* query = ws + WS_QUERY;
    float* Qtab  = ws + WS_QTAB;
    float* energy= ws + WS_ENERGY;
    float* ctx   = ws + WS_CTX;
    float* locI  = ws + WS_LOCI;
    float* Pws   = ws + WS_P;
    __bf16* enc_bf = (__bf16*)((char*)d_ws + (size_t)WS_F32_END * 4);
    __bf16* wk_bf  = enc_bf + (size_t)BS * TS * VDIM;
    __bf16* wv_bf  = wk_bf + (size_t)NHD * VDIM;
    __bf16* value  = wv_bf + (size_t)NHD * VDIM;
    const bool big = ws_size >= WS_NEED_BIG;

    // zero atomic accumulators (energy + ctx contiguous; ctx only needed
    // for the fallback path but cheap to always clear)
    hipMemsetAsync(energy, 0, (65536 + 16384) * sizeof(float), stream);

    k_precvt<<<dim3(NCVT + BS * NHD / 4), dim3(256), 0, stream>>>(
        enc, Wk, Wv, enc_bf, wk_bf, wv_bf, dec, Wq, bq, query);
    k_prefix<<<dim3(1), dim3(128), 0, stream>>>(convw, Pws);
    k_qtab<<<dim3(2 * KS + 2), dim3(512), 0, stream>>>(Pws, projw, Qtab);
    k_locI<<<dim3(BS * DIM / 256), dim3(256), 0, stream>>>(Qtab, enc_len, locI);
    if (big) {
        k_fused<true><<<dim3(TS / 128, NHD / 128, BS), dim3(512), 0, stream>>>(
            enc_bf, wk_bf, wv_bf, bk, bv, gen_w, enc_len, query, Qtab, locI,
            energy, value);
        k_softmax<<<dim3(BS * NH), dim3(512), 0, stream>>>(energy, enc_len, gen_b, out);
        k_ctxv<<<dim3(NHD / 128, BS), dim3(512), 0, stream>>>(
            value, out, enc_len, ctx);
    } else {
        k_fused<false><<<dim3(TS / 128, NHD / 128, BS), dim3(512), 0, stream>>>(
            enc_bf, wk_bf, wv_bf, bk, bv, gen_w, enc_len, query, Qtab, locI,
            energy, nullptr);
        k_softmax<<<dim3(BS * NH), dim3(512), 0, stream>>>(energy, enc_len, gen_b, out);
        k_ctxg<<<dim3(TS / 128, NHD / 128, BS), dim3(512), 0, stream>>>(
            enc_bf, wv_bf, bv, out, enc_len, ctx);
    }
    k_merge<<<dim3(BS * VDIM / 4), dim3(256), 0, stream>>>(ctx, merge_w, merge_b, out + 65536);
}

// Round 8
// 330.464 us; speedup vs baseline: 1.1361x; 1.0874x over previous
//
#include <hip/hip_runtime.h>
#include <math.h>

#define NH 4
#define DIM 512
#define VDIM 512
#define QDIM 1024
#define KS 100
#define KN 100
#define TEMPERATURE 0.5f
#define BS 8
#define TS 2048
#define NHD (NH * DIM)          // 2048

// workspace layout (floats)
#define WS_QUERY  0                       // 16384
#define WS_QTAB   16384                   // 202*512 = 103424
#define WS_ENERGY 119808                  // 65536
#define WS_CTX    185344                  // 16384
#define WS_P      201728                  // 202*100 = 20200
#define WS_F32_END 221928                 // *4 bytes
// bf16 region: enc_bf [8388608 el], wk_bf [1048576], wv_bf [1048576]

typedef __bf16 bf16x8 __attribute__((ext_vector_type(8)));
typedef __bf16 bf16x4 __attribute__((ext_vector_type(4)));
typedef float  f32x4  __attribute__((ext_vector_type(4)));

#define AS1(p) ((const __attribute__((address_space(1))) void*)(p))
#define AS3(p) ((__attribute__((address_space(3))) void*)(p))

__device__ __forceinline__ float fast_tanh(float x) {
    float xc = fminf(fmaxf(x, -9.0f), 9.0f);
    float e = __expf(2.0f * xc);
    return __fdividef(e - 1.0f, e + 1.0f);
}

// ---------------------------------------------------------------------------
// merged: fp32->bf16 cvt (3 tensors) + query GEMV + conv prefix, one dispatch
// ---------------------------------------------------------------------------
#define NE4 (BS * TS * VDIM / 4)      // 2097152
#define NW4 (NHD * VDIM / 4)          // 262144
#define NCVT ((NE4 + 2 * NW4) / 256)  // 10240 cvt blocks
#define NQRY (BS * NHD / 4)           // 4096 query blocks
__global__ void k_precvt(const float* __restrict__ enc, const float* __restrict__ Wk,
                         const float* __restrict__ Wv, __bf16* __restrict__ enc_bf,
                         __bf16* __restrict__ wk_bf, __bf16* __restrict__ wv_bf,
                         const float* __restrict__ dec, const float* __restrict__ Wq,
                         const float* __restrict__ bq, float* __restrict__ query,
                         const float* __restrict__ convw, float* __restrict__ P) {
    if (blockIdx.x < NCVT) {
        int i = blockIdx.x * blockDim.x + threadIdx.x;
        const float* src; __bf16* dst; int k;
        if (i < NE4)            { src = enc; dst = enc_bf; k = i; }
        else if (i < NE4 + NW4) { src = Wk;  dst = wk_bf;  k = i - NE4; }
        else                    { src = Wv;  dst = wv_bf;  k = i - NE4 - NW4; }
        float4 v = ((const float4*)src)[k];
        bf16x4 o;
        o[0] = (__bf16)v.x; o[1] = (__bf16)v.y; o[2] = (__bf16)v.z; o[3] = (__bf16)v.w;
        ((bf16x4*)dst)[k] = o;
    } else if (blockIdx.x < NCVT + NQRY) {
        int q = blockIdx.x - NCVT;                       // 0..4095
        int w = q * 4 + (threadIdx.x >> 6);              // wave id = output id
        int lane = threadIdx.x & 63;
        int b = w >> 11;
        int o = w & 2047;
        const float* dr = dec + b * QDIM;
        const float* wr = Wq + o * QDIM;
        float s = 0.f;
        #pragma unroll
        for (int i = 0; i < QDIM / 64; ++i)
            s = fmaf(dr[lane + 64 * i], wr[lane + 64 * i], s);
        #pragma unroll
        for (int off = 32; off > 0; off >>= 1) s += __shfl_down(s, off);
        if (lane == 0) query[b * NHD + o] = tanhf(s + bq[o]);
    } else {
        // conv prefix: P[j][k] = sum_{dt<j} sum_h convw[k,h,dt]
        int k = threadIdx.x;
        if (k < KN) {
            const float* wr = convw + k * (NH * (2 * KS + 1));
            float acc = 0.f;
            P[k] = 0.f;
            for (int dt = 0; dt < 2 * KS + 1; ++dt) {
                acc += wr[dt] + wr[201 + dt] + wr[402 + dt] + wr[603 + dt];
                P[(dt + 1) * KN + k] = acc;
            }
        }
    }
}

// ---------------------------------------------------------------------------
// Qtab[j,d] = sum_k projw[d,k] * P[j,k]
// ---------------------------------------------------------------------------
__global__ void k_qtab(const float* __restrict__ P, const float* __restrict__ projw,
                       float* __restrict__ Qtab) {
    int j = blockIdx.x;       // 0..201
    __shared__ float Pc[KN];
    int tid = threadIdx.x;    // 512
    if (tid < KN) Pc[tid] = P[j * KN + tid];
    __syncthreads();
    const float* pr = projw + tid * KN;
    float s = 0.f;
    #pragma unroll 4
    for (int k = 0; k < KN; ++k) s = fmaf(pr[k], Pc[k], s);
    Qtab[j * DIM + tid] = s;
}

// ===========================================================================
// GEMM core: 128x128 tile, BK=32, 512 threads (8 waves 2x4, wave tile 64x32),
// double-buffered LDS (32 KB total -> 4 blocks/CU), one barrier/iter,
// loop-invariant addresses (BK=32 makes the XOR swizzle i/k-independent).
// XCD-pinned flat grid: bid = ((b*16 + t0b)*2 + nhi)*8 + nlo, so XCD = nlo
// holds a 256 KB B slice L2-resident, and the 16 blocks sharing an A tile
// (bits [3:0]) run in the same time window -> A served once from L3.
// ===========================================================================
#define GEMM1(Bptr)                                                               \
    const int bid = blockIdx.x;                                                    \
    const int b   = bid >> 8;                                                      \
    const int t0  = ((bid >> 4) & 15) << 7;                                        \
    const int n0  = ((((bid >> 3) & 1) << 3) | (bid & 7)) << 7;                    \
    const int len = enc_len[b];                                                    \
    if (t0 >= len) return;                                                         \
    const int tid = threadIdx.x;                                                   \
    const int w = tid >> 6, lane = tid & 63;                                       \
    const int wy = w >> 2, wx = w & 3;                                             \
    const int col = lane & 15, quad = lane >> 4;                                   \
    __shared__ __bf16 Ash[2 * 4096];                                               \
    __shared__ __bf16 Bsh[2 * 4096];                                               \
    f32x4 acc[4][2];                                                               \
    _Pragma("unroll")                                                              \
    for (int i = 0; i < 4; ++i)                                                    \
        _Pragma("unroll")                                                          \
        for (int j = 0; j < 2; ++j) acc[i][j] = (f32x4)0.f;                        \
    const __bf16* Abase = enc_bf + ((size_t)b * TS + t0) * VDIM;                   \
    const int sm = tid >> 2;                                                       \
    const int sj = (tid & 3) ^ (sm & 3) ^ ((sm >> 2) & 3);                         \
    const __bf16* gpA = Abase + (size_t)sm * VDIM + sj * 8;                        \
    const __bf16* gpB = (Bptr) + ((size_t)n0 + sm) * VDIM + sj * 8;                \
    const int cfr = quad ^ (col & 3) ^ ((col >> 2) & 3);                           \
    const char* pA = (const char*)Ash + (((wy * 64 + col) * 4 + cfr) << 4);        \
    const char* pB = (const char*)Bsh + (((wx * 32 + col) * 4 + cfr) << 4);        \
    __builtin_amdgcn_global_load_lds(AS1(gpA), AS3(Ash + w * 512), 16, 0, 0);      \
    __builtin_amdgcn_global_load_lds(AS1(gpB), AS3(Bsh + w * 512), 16, 0, 0);      \
    gpA += 32; gpB += 32;                                                          \
    for (int kk = 0; kk < 16; ++kk) {                                              \
        __syncthreads();                                                           \
        if (kk < 15) {                                                             \
            int nb_ = ((kk + 1) & 1) * 4096;                                       \
            __builtin_amdgcn_global_load_lds(AS1(gpA), AS3(Ash + nb_ + w * 512), 16, 0, 0); \
            __builtin_amdgcn_global_load_lds(AS1(gpB), AS3(Bsh + nb_ + w * 512), 16, 0, 0); \
            gpA += 32; gpB += 32;                                                  \
        }                                                                          \
        const int bo = (kk & 1) * 8192;                                            \
        bf16x8 af[4], bfr[2];                                                      \
        _Pragma("unroll")                                                          \
        for (int i = 0; i < 4; ++i) af[i] = *(const bf16x8*)(pA + bo + i * 1024);  \
        _Pragma("unroll")                                                          \
        for (int j = 0; j < 2; ++j) bfr[j] = *(const bf16x8*)(pB + bo + j * 1024); \
        _Pragma("unroll")                                                          \
        for (int i = 0; i < 4; ++i)                                                \
            _Pragma("unroll")                                                      \
            for (int j = 0; j < 2; ++j)                                            \
                acc[i][j] = __builtin_amdgcn_mfma_f32_16x16x32_bf16(               \
                    af[i], bfr[j], acc[i][j], 0, 0, 0);                            \
    }                                                                              \
    __syncthreads();
// acc[i][j][r] = C[t0+wy*64+i*16+quad*4+r][n0+wx*32+j*16+col]

// ---------------------------------------------------------------------------
// Energy pass: C = enc @ Wk^T, epilogue:
//   energy[b,h,t] += sum_n tanh(tanh(C+bk)+query+loc) * gen_w[d]
// ---------------------------------------------------------------------------
__global__ __launch_bounds__(512, 4) void k_energy(
    const __bf16* __restrict__ enc_bf, const __bf16* __restrict__ wk_bf,
    const float* __restrict__ bk, const float* __restrict__ gen_w,
    const int* __restrict__ enc_len, const float* __restrict__ query,
    const float* __restrict__ Qtab, float* __restrict__ energy) {
    GEMM1(wk_bf)

    const int h = n0 >> 9;
    const float inv_len = 1.0f / (float)len;
    float qv[2], gw[2], bkv[2], lI[2];
    int dj[2];
    #pragma unroll
    for (int j = 0; j < 2; ++j) {
        int n = n0 + wx * 32 + j * 16 + col;
        dj[j] = n & (DIM - 1);
        qv[j] = query[b * NHD + n];
        gw[j] = gen_w[dj[j]];
        bkv[j] = bk[n];
        lI[j] = fast_tanh((Qtab[(2 * KS + 1) * DIM + dj[j]] - Qtab[dj[j]]) * inv_len);
    }
    float* red = (float*)Ash;   // [128][4]
    #pragma unroll
    for (int i = 0; i < 4; ++i) {
        #pragma unroll
        for (int r = 0; r < 4; ++r) {
            int tl = wy * 64 + i * 16 + quad * 4 + r;
            int t = t0 + tl;
            float l[2];
            if (t >= KS && t < len - KS) {           // interior: loc const in t
                #pragma unroll
                for (int j = 0; j < 2; ++j) l[j] = lI[j];
            } else {
                int lo = KS - t; if (lo < 0) lo = 0;
                int hi = KS - t + len - 1; if (hi > 2 * KS) hi = 2 * KS;
                bool has = (hi >= lo);
                #pragma unroll
                for (int j = 0; j < 2; ++j) {
                    float cv = has
                        ? (Qtab[(hi + 1) * DIM + dj[j]] - Qtab[lo * DIM + dj[j]]) * inv_len
                        : 0.f;
                    l[j] = fast_tanh(cv);
                }
            }
            float s = 0.f;
            #pragma unroll
            for (int j = 0; j < 2; ++j) {
                float key = fast_tanh(acc[i][j][r] + bkv[j]);
                float e = fast_tanh(key + qv[j] + l[j]);
                s = fmaf(e, gw[j], s);
            }
            s += __shfl_xor(s, 1); s += __shfl_xor(s, 2);
            s += __shfl_xor(s, 4); s += __shfl_xor(s, 8);
            if (col == 0) red[tl * 4 + wx] = s;
        }
    }
    __syncthreads();
    if (tid < 128) {
        float s = red[tid * 4] + red[tid * 4 + 1] + red[tid * 4 + 2] + red[tid * 4 + 3];
        atomicAdd(&energy[(size_t)(b * NH + h) * TS + t0 + tid], s);
    }
}

// ---------------------------------------------------------------------------
// ctx pass: C = enc @ Wv^T, epilogue: ctx[b,n] += sum_t attn * tanh(C + bv)
// ---------------------------------------------------------------------------
__global__ __launch_bounds__(512, 4) void k_ctxg(
    const __bf16* __restrict__ enc_bf, const __bf16* __restrict__ wv_bf,
    const float* __restrict__ bv, const float* __restrict__ attn,
    const int* __restrict__ enc_len, float* __restrict__ ctx) {
    GEMM1(wv_bf)

    const int h = n0 >> 9;
    float att[4][4];
    #pragma unroll
    for (int i = 0; i < 4; ++i)
        #pragma unroll
        for (int r = 0; r < 4; ++r)
            att[i][r] = attn[(size_t)(b * NH + h) * TS + t0 + wy * 64 + i * 16 + quad * 4 + r];
    float* red = (float*)Ash;   // [128][2]
    #pragma unroll
    for (int j = 0; j < 2; ++j) {
        int nl = wx * 32 + j * 16 + col;
        float bvn = bv[n0 + nl];
        float s = 0.f;
        #pragma unroll
        for (int i = 0; i < 4; ++i)
            #pragma unroll
            for (int r = 0; r < 4; ++r)
                s = fmaf(att[i][r], fast_tanh(acc[i][j][r] + bvn), s);
        s += __shfl_xor(s, 16); s += __shfl_xor(s, 32);
        if (quad == 0) red[nl * 2 + wy] = s;
    }
    __syncthreads();
    if (tid < 128) {
        float s = red[tid * 2] + red[tid * 2 + 1];
        atomicAdd(&ctx[(size_t)b * NHD + n0 + tid], s);
    }
}

// ---------------------------------------------------------------------------
// softmax over t (masked), shuffle-based, writes attn to d_out
// ---------------------------------------------------------------------------
__global__ void k_softmax(const float* __restrict__ energy, const int* __restrict__ enc_len,
                          const float* __restrict__ gen_b, float* __restrict__ attn) {
    int bh = blockIdx.x;          // 32
    int b = bh >> 2;
    int len = enc_len[b];
    int tid = threadIdx.x;        // 512
    int w = tid >> 6, lane = tid & 63;
    const float gb = gen_b[0];
    float ev[4];
    float mx = -INFINITY;
    #pragma unroll
    for (int i = 0; i < 4; ++i) {
        int t = i * 512 + tid;
        float e = (t < len) ? (energy[(size_t)bh * TS + t] + gb) * (1.0f / TEMPERATURE)
                            : -INFINITY;
        ev[i] = e;
        mx = fmaxf(mx, e);
    }
    __shared__ float sred[8], ssum[8];
    #pragma unroll
    for (int off = 32; off > 0; off >>= 1) mx = fmaxf(mx, __shfl_xor(mx, off));
    if (lane == 0) sred[w] = mx;
    __syncthreads();
    #pragma unroll
    for (int k = 0; k < 8; ++k) mx = fmaxf(mx, sred[k]);
    float ls = 0.f;
    #pragma unroll
    for (int i = 0; i < 4; ++i) {
        float ex = __expf(ev[i] - mx);
        ev[i] = ex;
        ls += ex;
    }
    #pragma unroll
    for (int off = 32; off > 0; off >>= 1) ls += __shfl_xor(ls, off);
    if (lane == 0) ssum[w] = ls;
    __syncthreads();
    float tot = 0.f;
    #pragma unroll
    for (int k = 0; k < 8; ++k) tot += ssum[k];
    float inv = 1.0f / tot;
    #pragma unroll
    for (int i = 0; i < 4; ++i)
        attn[(size_t)bh * TS + i * 512 + tid] = ev[i] * inv;
}

// ---------------------------------------------------------------------------
// context[b,o] = ctx[b,:] . merge_w[o,:] + merge_b[o];  one wave per output
// ---------------------------------------------------------------------------
__global__ void k_merge(const float* __restrict__ ctx, const float* __restrict__ mw,
                        const float* __restrict__ mb, float* __restrict__ out) {
    int w = (blockIdx.x * blockDim.x + threadIdx.x) >> 6;
    int lane = threadIdx.x & 63;
    int b = w >> 9;
    int o = w & 511;
    const float* c = ctx + (size_t)b * NHD;
    const float* wr = mw + (size_t)o * NHD;
    float s = 0.f;
    #pragma unroll
    for (int i = 0; i < NHD / 64; ++i) s = fmaf(c[lane + 64 * i], wr[lane + 64 * i], s);
    #pragma unroll
    for (int off = 32; off > 0; off >>= 1) s += __shfl_down(s, off);
    if (lane == 0) out[b * VDIM + o] = s + mb[o];
}

extern "C" void kernel_launch(void* const* d_in, const int* in_sizes, int n_in,
                              void* d_out, int out_size, void* d_ws, size_t ws_size,
                              hipStream_t stream) {
    const float* dec     = (const float*)d_in[0];
    const float* enc     = (const float*)d_in[1];
    const int*   enc_len = (const int*)d_in[2];
    const float* Wq      = (const float*)d_in[3];
    const float* bq      = (const float*)d_in[4];
    const float* Wk      = (const float*)d_in[5];
    const float* bk      = (const float*)d_in[6];
    const float* Wv      = (const float*)d_in[7];
    const float* bv      = (const float*)d_in[8];
    const float* convw   = (const float*)d_in[9];
    const float* projw   = (const float*)d_in[10];
    const float* gen_w   = (const float*)d_in[11];
    const float* gen_b   = (const float*)d_in[12];
    const float* merge_w = (const float*)d_in[13];
    const float* merge_b = (const float*)d_in[14];

    float* out   = (float*)d_out;               // attn [65536] ++ context [4096]
    float* ws    = (float*)d_ws;
    float* query = ws + WS_QUERY;
    float* Qtab  = ws + WS_QTAB;
    float* energy= ws + WS_ENERGY;
    float* ctx   = ws + WS_CTX;
    float* Pws   = ws + WS_P;
    __bf16* enc_bf = (__bf16*)((char*)d_ws + (size_t)WS_F32_END * 4);
    __bf16* wk_bf  = enc_bf + (size_t)BS * TS * VDIM;
    __bf16* wv_bf  = wk_bf + (size_t)NHD * VDIM;

    // zero atomic accumulators (energy + ctx contiguous)
    hipMemsetAsync(energy, 0, (65536 + 16384) * sizeof(float), stream);

    k_precvt<<<dim3(NCVT + NQRY + 1), dim3(256), 0, stream>>>(
        enc, Wk, Wv, enc_bf, wk_bf, wv_bf, dec, Wq, bq, query, convw, Pws);
    k_qtab<<<dim3(2 * KS + 2), dim3(512), 0, stream>>>(Pws, projw, Qtab);
    k_energy<<<dim3(2048), dim3(512), 0, stream>>>(
        enc_bf, wk_bf, bk, gen_w, enc_len, query, Qtab, energy);
    k_softmax<<<dim3(BS * NH), dim3(512), 0, stream>>>(energy, enc_len, gen_b, out);
    k_ctxg<<<dim3(2048), dim3(512), 0, stream>>>(
        enc_bf, wv_bf, bv, out, enc_len, ctx);
    k_merge<<<dim3(BS * VDIM / 4), dim3(256), 0, stream>>>(ctx, merge_w, merge_b, out + 65536);
}